// Round 6
// baseline (473.284 us; speedup 1.0000x reference)
//
#include <hip/hip_runtime.h>
#include <stdint.h>

typedef _Float16 f16;
typedef _Float16 f16x8 __attribute__((ext_vector_type(8)));
typedef _Float16 f16x4 __attribute__((ext_vector_type(4)));
typedef float f32x4 __attribute__((ext_vector_type(4)));

#define GAS __attribute__((address_space(1)))
#define LAS __attribute__((address_space(3)))

// async global->LDS, 16 B per lane; LDS dest = wave-uniform base + lane*16
__device__ __forceinline__ void gl_lds16(const void* g, void* l) {
    __builtin_amdgcn_global_load_lds((const GAS uint32_t*)g, (LAS uint32_t*)l, 16, 0, 0);
}

__global__ __launch_bounds__(256) void zerof(float* __restrict__ p, int n) {
    int i = blockIdx.x * 256 + threadIdx.x;
    if (i < n) p[i] = 0.f;
}

__global__ __launch_bounds__(256) void cvt16(const float* __restrict__ in,
                                             f16* __restrict__ o, long n) {
    long i = (long)blockIdx.x * 256 + threadIdx.x;
    if (i < n) o[i] = (f16)in[i];
}

// w [27][Cin][Cout] fp32 -> wt [27][Cout][Cin] fp16 (B-fragment: 16B contiguous Cin)
__global__ __launch_bounds__(256) void wtrans16(const float* __restrict__ w,
                                                f16* __restrict__ wt,
                                                int Cin, int Cout) {
    long i = (long)blockIdx.x * 256 + threadIdx.x;
    long total = 27L * Cin * Cout;
    if (i >= total) return;
    int ci = (int)(i % Cin);
    long t = i / Cin;
    int co = (int)(t % Cout);
    int k  = (int)(t / Cout);
    wt[i] = (f16)w[((long)k * Cin + ci) * Cout + co];
}

// ---------------------------------------------------------------------------
// conv_dense<0>: round-2 proven structure (A dbuf 46 KB x2 + B dbuf, per-tap
// __syncthreads, 1 block/CU). Used ONLY for spconv1 (CIN=256 -> 128).
// ---------------------------------------------------------------------------
template <int LAYER>
__global__ __launch_bounds__(512, 2) void conv_dense(
    const f16* __restrict__ fin, const f16* __restrict__ wt,
    const f16* __restrict__ zrow, float* __restrict__ out,
    float* __restrict__ stats) {
    constexpr int COUT = 128;
    constexpr int INRB = 512;            // input row bytes (256 ch)
    constexpr int WRB  = 512;            // weight row bytes per col
    constexpr int RT   = 4;
    constexpr int CT   = 4;
    constexpr int NBCH = COUT / 4;       // B chunks (1 KB each)
    extern __shared__ char smem[];
    char* ldsA0 = smem;                  // 46080
    char* ldsA1 = smem + 46080;          // 46080
    char* ldsB0 = smem + 92160;          // COUT*256
    char* ldsB1 = smem + 92160 + COUT * 256;

    const int b = blockIdx.x;
    const int p = b / 72;                // out plane
    const int t0 = b % 72;
    const int y0 = (t0 / 6) * 8;
    const int x0 = (t0 % 6) * 16;
    const int tid = threadIdx.x;
    const int lane = tid & 63;
    const int wave = tid >> 6;
    const int kh = wave & 1;
    const int pairId = wave >> 1;
    const int q = lane >> 4;
    const int r16 = lane & 15;
    const int wr = (pairId >> 1) * (RT * 16);
    const int wc = (pairId & 1) * (CT * 16);

    // stages: 2 channel halves of the single in-plane (dz = 1-p)
    const int S = 2;
    int js[2] = {0, 0}, dzs[2] = {1 - p, 1 - p}, hs[2] = {0, 1};

    auto stageA = [&](int s, char* buf) {
        const int j = js[s], h = hs[s];
        const long pbase = (long)j * 9216;
        for (int ch = wave; ch < 45; ch += 8) {
            int site = ch * 4 + q;
            int sy = site / 18;
            int sx = site - sy * 18;
            int y = y0 - 1 + sy;
            int x = x0 - 1 + sx;
            int cc = r16 ^ (site & 7);
            bool ok = ((unsigned)y < 96u) & ((unsigned)x < 96u);
            const char* src = ok
                ? (const char*)fin + (pbase + y * 96 + x) * INRB + h * 256 + cc * 16
                : (const char*)zrow + cc * 16;
            gl_lds16(src, buf + ch * 1024);
        }
    };
    auto stageB = [&](int k, int h, char* buf) {
        for (int ch = wave; ch < NBCH; ch += 8) {
            int col = ch * 4 + q;
            int cc = r16 ^ (col & 7);
            const char* src = (const char*)wt + (long)(k * COUT + col) * WRB +
                              h * 256 + cc * 16;
            gl_lds16(src, buf + ch * 1024);
        }
    };

    f32x4 acc[RT][CT];
#pragma unroll
    for (int tr = 0; tr < RT; tr++)
#pragma unroll
        for (int c = 0; c < CT; c++) acc[tr][c] = f32x4{0.f, 0.f, 0.f, 0.f};

    stageA(0, ldsA0);
    stageB((dzs[0] + 1) * 9, hs[0], ldsB0);

    int tap = 0;
    for (int s = 0; s < S; s++) {
        const char* bufA = (s & 1) ? ldsA1 : ldsA0;
#pragma unroll
        for (int i = 0; i < 9; i++, tap++) {
            __syncthreads();
            if (i == 0 && s + 1 < S) stageA(s + 1, ((s + 1) & 1) ? ldsA1 : ldsA0);
            if (tap + 1 < S * 9) {
                int sn = (i == 8) ? s + 1 : s;
                int in2 = (i == 8) ? 0 : i + 1;
                stageB((dzs[sn] + 1) * 9 + in2, hs[sn], ((tap + 1) & 1) ? ldsB1 : ldsB0);
            }
            const char* bufB = (tap & 1) ? ldsB1 : ldsB0;
            const int dy = i / 3 - 1, dx = i % 3 - 1;
#pragma unroll
            for (int kk2 = 0; kk2 < 2; kk2++) {
                const int kk = kh * 2 + kk2;
                f16x8 Af[RT], Bf[CT];
#pragma unroll
                for (int tr = 0; tr < RT; tr++) {
                    int site = (wr / 16 + tr + 1 + dy) * 18 + 1 + dx + r16;
                    Af[tr] = *(const f16x8*)(bufA + site * 256 +
                                             (((kk * 4 + q) ^ (site & 7)) << 4));
                }
#pragma unroll
                for (int c = 0; c < CT; c++) {
                    int col = wc + c * 16 + r16;
                    Bf[c] = *(const f16x8*)(bufB + col * 256 +
                                            (((kk * 4 + q) ^ (col & 7)) << 4));
                }
#pragma unroll
                for (int tr = 0; tr < RT; tr++)
#pragma unroll
                    for (int c = 0; c < CT; c++)
                        acc[tr][c] = __builtin_amdgcn_mfma_f32_16x16x32_f16(
                            Af[tr], Bf[c], acc[tr][c], 0, 0, 0);
            }
        }
    }

    // K-half (kh) reduction via LDS park in dead buffers
    char* xch = smem + 92160;
    constexpr int XR = RT * CT * 1024;
    __syncthreads();
    if (kh == 1) {
#pragma unroll
        for (int tr = 0; tr < RT; tr++)
#pragma unroll
            for (int c = 0; c < CT; c++)
                *(f32x4*)(xch + pairId * XR + (tr * CT + c) * 1024 + lane * 16) =
                    acc[tr][c];
    }
    __syncthreads();
    if (kh == 1) return;
#pragma unroll
    for (int tr = 0; tr < RT; tr++)
#pragma unroll
        for (int c = 0; c < CT; c++)
            acc[tr][c] += *(const f32x4*)(xch + pairId * XR + (tr * CT + c) * 1024 +
                                          lane * 16);

    const long mbase = (long)p * 9216 + (long)y0 * 96 + x0;
#pragma unroll
    for (int c = 0; c < CT; c++) {
        const int col = wc + c * 16 + r16;
        float sum = 0.f, ssq = 0.f;
#pragma unroll
        for (int tr = 0; tr < RT; tr++) {
            const int ly = wr / 16 + tr;
#pragma unroll
            for (int r = 0; r < 4; r++) {
                const int lx = q * 4 + r;
                float v = acc[tr][c][r];
                out[(mbase + ly * 96 + lx) * COUT + col] = v;
                sum += v;
                ssq = fmaf(v, v, ssq);
            }
        }
        sum += __shfl_xor(sum, 16);
        sum += __shfl_xor(sum, 32);
        ssq += __shfl_xor(ssq, 16);
        ssq += __shfl_xor(ssq, 32);
        if (q == 0) {
            atomicAdd(&stats[col], sum);
            atomicAdd(&stats[COUT + col], ssq);
        }
    }
}

// ---------------------------------------------------------------------------
// conv_ks<LAYER>: K-SPLIT ACROSS BLOCKS. blockIdx&1 = kb owns 64 of the 128
// input channels; per-block LDS halves -> 2 (LAYER1) / 3-4 (LAYER2) blocks/CU
// co-resident, whose independent barrier domains hide each other's stalls
// (the m97 mechanism). Per-CU LDS read traffic per tap is IDENTICAL to the
// round-2 single-block config. Tap/sync structure = round-2 proven pattern.
// Partials written to out1 (kb=0) / out2 (kb=1); BN stats computed later by
// bnstats (ssq is nonlinear in the partials).
//  A': 10y x 18x sites x 128 B (64 ch) = 23 KB (padded 23552), dbuf for L1,
//      single for L2 (reloaded between double barriers at stage boundaries).
//  B:  [COUT][64 ch] panels (16 KB / 4 KB), double-buffered per tap.
//  Waves: 8 = pair(rg x ch for L1 / 4 rg for L2) x kh; wave kh reads channel
//  chunk kh of the block's 64 ch (single kk step per tap).
// LAYER 1: CIN half=64, 3 in-planes j=p+dz,   COUT=128, grid 2*216
// LAYER 2: CIN half=64, 3 in-planes j=p+dz-1, COUT=32,  grid 2*360
// ---------------------------------------------------------------------------
template <int LAYER>
__global__ __launch_bounds__(512, (LAYER == 2) ? 6 : 4) void conv_ks(
    const f16* __restrict__ fin, const f16* __restrict__ wt,
    const f16* __restrict__ zrow, float* __restrict__ out1,
    float* __restrict__ out2) {
    constexpr int COUT = (LAYER == 2) ? 32 : 128;
    constexpr int RT   = (COUT == 128) ? 4 : 2;
    constexpr int CT   = (COUT == 128) ? 4 : 2;
    constexpr int ASLAB = 23552;         // 184 sites x 128 B (180 used)
    constexpr int BPAN  = COUT * 128;    // 16 KB / 4 KB
    constexpr int NBG   = COUT / 8;      // 1 KB B groups: 16 / 4
    extern __shared__ char smem[];
    char* ldsA0 = smem;
    char* ldsA1 = (LAYER == 1) ? smem + ASLAB : smem;   // L2: single (alias)
    char* ldsB  = smem + ((LAYER == 1) ? 2 * ASLAB : ASLAB);

    const int b = blockIdx.x;
    const int kb = b & 1;                // K-half of the input channels
    const int t = b >> 1;
    const int p = t / 72;                // out plane
    const int t0 = t % 72;
    const int y0 = (t0 / 6) * 8;
    const int x0 = (t0 % 6) * 16;
    const int tid = threadIdx.x;
    const int lane = tid & 63;
    const int wave = tid >> 6;           // 0..7
    const int kh = wave & 1;             // channel chunk within the 64-ch half
    const int pairId = wave >> 1;        // 0..3
    const int q = lane >> 4;
    const int r16 = lane & 15;
    const int wr = ((COUT == 128) ? (pairId >> 1) : pairId) * (RT * 16);
    const int wc = ((COUT == 128) ? (pairId & 1) : 0) * (CT * 16);

    int S = 0;
    int js[3], dzs[3];
    for (int dz = -1; dz <= 1; dz++) {
        int j = (LAYER == 1) ? p + dz : p + dz - 1;
        if (0 <= j && j < 3) { js[S] = j; dzs[S] = dz; S++; }
    }

    auto stageA = [&](int s, char* buf) {
        const int j = js[s];
        const long pbase = (long)j * 9216;
        for (int g = wave; g < 23; g += 8) {
            int site = g * 8 + (lane >> 3);
            int sy = site / 18;
            int sx = site - sy * 18;
            int y = y0 - 1 + sy;
            int x = x0 - 1 + sx;
            int cc = (lane & 7) ^ (site & 7);
            bool ok = ((unsigned)y < 96u) & ((unsigned)x < 96u) & (site < 180);
            const char* src = ok
                ? (const char*)fin + (pbase + y * 96 + x) * 256 + kb * 128 + cc * 16
                : (const char*)zrow + cc * 16;
            gl_lds16(src, buf + g * 1024);
        }
    };
    auto stageB = [&](int tg, char* buf) {
        const int sn = tg / 9, in2 = tg % 9;
        const int k = (dzs[sn] + 1) * 9 + in2;
        for (int g = wave; g < NBG; g += 8) {
            int col = g * 8 + (lane >> 3);
            int cc = (lane & 7) ^ (col & 7);
            const char* src = (const char*)wt + ((long)(k * COUT + col)) * 256 +
                              kb * 128 + cc * 16;
            gl_lds16(src, buf + g * 1024);
        }
    };

    f32x4 acc[RT][CT];
#pragma unroll
    for (int tr = 0; tr < RT; tr++)
#pragma unroll
        for (int c = 0; c < CT; c++) acc[tr][c] = f32x4{0.f, 0.f, 0.f, 0.f};

    const int T = S * 9;
    stageA(0, ldsA0);
    stageB(0, ldsB);

    int tap = 0;
    for (int s = 0; s < S; s++) {
        const char* bufA = (LAYER == 1) ? ((s & 1) ? ldsA1 : ldsA0) : ldsA0;
        if (LAYER == 2 && s > 0) {
            __syncthreads();             // prev-stage A reads done (+B drain ok)
            stageA(s, ldsA0);            // reload single slab
        }
#pragma unroll
        for (int i = 0; i < 9; i++, tap++) {
            __syncthreads();             // drains staged B(tap) (+A when due)
            if (LAYER == 1 && i == 0 && s + 1 < S)
                stageA(s + 1, ((s + 1) & 1) ? ldsA1 : ldsA0);
            if (tap + 1 < T) stageB(tap + 1, ldsB + ((tap + 1) & 1) * BPAN);
            const char* bufB = ldsB + (tap & 1) * BPAN;
            const int dy = i / 3 - 1, dx = i % 3 - 1;
            f16x8 Af[RT], Bf[CT];
#pragma unroll
            for (int tr = 0; tr < RT; tr++) {
                int site = (wr / 16 + tr + 1 + dy) * 18 + 1 + dx + r16;
                Af[tr] = *(const f16x8*)(bufA + site * 128 +
                                         (((kh * 4 + q) ^ (site & 7)) << 4));
            }
#pragma unroll
            for (int c = 0; c < CT; c++) {
                int col = wc + c * 16 + r16;
                Bf[c] = *(const f16x8*)(bufB + col * 128 +
                                        (((kh * 4 + q) ^ (col & 7)) << 4));
            }
#pragma unroll
            for (int tr = 0; tr < RT; tr++)
#pragma unroll
                for (int c = 0; c < CT; c++)
                    acc[tr][c] = __builtin_amdgcn_mfma_f32_16x16x32_f16(
                        Af[tr], Bf[c], acc[tr][c], 0, 0, 0);
        }
    }

    // kh reduction via LDS park (all DMA drained by last tap's syncthreads)
    char* xch = smem;
    constexpr int XR = RT * CT * 1024;
    __syncthreads();
    if (kh == 1) {
#pragma unroll
        for (int tr = 0; tr < RT; tr++)
#pragma unroll
            for (int c = 0; c < CT; c++)
                *(f32x4*)(xch + pairId * XR + (tr * CT + c) * 1024 + lane * 16) =
                    acc[tr][c];
    }
    __syncthreads();
    if (kh == 1) return;
#pragma unroll
    for (int tr = 0; tr < RT; tr++)
#pragma unroll
        for (int c = 0; c < CT; c++)
            acc[tr][c] += *(const f32x4*)(xch + pairId * XR + (tr * CT + c) * 1024 +
                                          lane * 16);

    float* po = kb ? out2 : out1;
    const long mbase = (long)p * 9216 + (long)y0 * 96 + x0;
#pragma unroll
    for (int c = 0; c < CT; c++) {
        const int col = wc + c * 16 + r16;
#pragma unroll
        for (int tr = 0; tr < RT; tr++) {
            const int ly = wr / 16 + tr;
#pragma unroll
            for (int r = 0; r < 4; r++) {
                const int lx = q * 4 + r;
                po[(mbase + ly * 96 + lx) * COUT + col] = acc[tr][c][r];
            }
        }
    }
}

// Per-channel sum/ssq of v = f + f2 (K-split partials). 512 thr = C ch x RL rows.
template <int C>
__global__ __launch_bounds__(512) void bnstats(
    const float* __restrict__ f, const float* __restrict__ f2,
    float* __restrict__ st, int rowsPer) {
    __shared__ float ls[512], lq[512];
    const int tid = threadIdx.x;
    const int ch = tid & (C - 1);
    const int rr = tid / C;
    constexpr int RL = 512 / C;
    const long r0 = (long)blockIdx.x * rowsPer;
    float sum = 0.f, ssq = 0.f;
    for (int r = rr; r < rowsPer; r += RL) {
        long idx = (r0 + r) * C + ch;
        float v = f[idx] + f2[idx];
        sum += v;
        ssq = fmaf(v, v, ssq);
    }
    ls[tid] = sum;
    lq[tid] = ssq;
    __syncthreads();
    if (tid < C) {
        float s = 0.f, qq = 0.f;
#pragma unroll
        for (int k = 0; k < RL; k++) { s += ls[ch + k * C]; qq += lq[ch + k * C]; }
        atomicAdd(&st[ch], s);
        atomicAdd(&st[C + ch], qq);
    }
}

// BN(train) + optional K-split partial add + optional residual + ReLU.
__global__ __launch_bounds__(256) void bn_apply4(
    const float4* __restrict__ f, const float4* __restrict__ f2,
    const float* __restrict__ sums, const float* __restrict__ g,
    const float* __restrict__ bta, const f16x4* __restrict__ idn,
    f16* __restrict__ outh, float4* __restrict__ outf,
    long n4, int C, float invM) {
    long i = (long)blockIdx.x * 256 + threadIdx.x;
    if (i >= n4) return;
    int col0 = (int)((i * 4) & (C - 1));
    float4 v = f[i];
    if (f2) {
        float4 w = f2[i];
        v.x += w.x; v.y += w.y; v.z += w.z; v.w += w.w;
    }
    float r[4] = {v.x, v.y, v.z, v.w};
    f16x4 id = {};
    if (idn) id = idn[i];
    f16x4 ho;
#pragma unroll
    for (int j = 0; j < 4; j++) {
        int c = col0 + j;
        float mu = sums[c] * invM;
        float var = sums[C + c] * invM - mu * mu;
        var = fmaxf(var, 0.f);
        float sc = g[c] * rsqrtf(var + 1e-5f);
        float x = (r[j] - mu) * sc + bta[c];
        if (idn) x += (float)id[j];
        x = fmaxf(x, 0.f);
        r[j] = x;
        ho[j] = (f16)x;
    }
    if (outf) outf[i] = make_float4(r[0], r[1], r[2], r[3]);
    else *(f16x4*)(outh + i * 4) = ho;
}

extern "C" void kernel_launch(void* const* d_in, const int* in_sizes, int n_in,
                              void* d_out, int out_size, void* d_ws, size_t ws_size,
                              hipStream_t stream) {
    (void)n_in; (void)out_size; (void)ws_size;
    const float* x    = (const float*)d_in[0];
    const float* w_s1 = (const float*)d_in[1];
    const float* g_s1 = (const float*)d_in[2];
    const float* b_s1 = (const float*)d_in[3];
    const float* w11  = (const float*)d_in[4];
    const float* g11  = (const float*)d_in[5];
    const float* b11  = (const float*)d_in[6];
    const float* w12  = (const float*)d_in[7];
    const float* g12  = (const float*)d_in[8];
    const float* b12  = (const float*)d_in[9];
    const float* w21  = (const float*)d_in[10];
    const float* g21  = (const float*)d_in[11];
    const float* b21  = (const float*)d_in[12];
    const float* w22  = (const float*)d_in[13];
    const float* g22  = (const float*)d_in[14];
    const float* b22  = (const float*)d_in[15];
    const float* w_s2 = (const float*)d_in[16];
    const float* g_s2 = (const float*)d_in[17];
    const float* b_s2 = (const float*)d_in[18];

    const int N0 = in_sizes[0] / 256;   // 9216
    const int M1 = in_sizes[19] / 27;   // 27648
    const int M2 = in_sizes[21] / 27;   // 46080

    char* base = (char*)d_ws;
    size_t off = 0;
    auto alloc = [&](size_t bytes) -> char* {
        off = (off + 255) & ~(size_t)255;
        char* p = base + off;
        off += bytes;
        return p;
    };
    f16* xh  = (f16*)alloc((size_t)N0 * 256 * 2);
    f16* w1  = (f16*)alloc(27UL * 128 * 256 * 2);
    f16* wa1 = (f16*)alloc(27UL * 128 * 128 * 2);
    f16* wa2 = (f16*)alloc(27UL * 128 * 128 * 2);
    f16* wb1 = (f16*)alloc(27UL * 128 * 128 * 2);
    f16* wb2 = (f16*)alloc(27UL * 128 * 128 * 2);
    f16* w2  = (f16*)alloc(27UL * 32 * 128 * 2);
    f16* fA  = (f16*)alloc((size_t)M1 * 128 * 2);
    f16* fB  = (f16*)alloc((size_t)M1 * 128 * 2);
    float* cbuf  = (float*)alloc((size_t)M1 * 128 * 4);  // partial kb=0
    float* cbuf2 = (float*)alloc((size_t)M1 * 128 * 4);  // partial kb=1
    float* stats = (float*)alloc(1344UL * 4);            // per-layer sum/ssq
    f16*   zrow  = (f16*)alloc(512);                     // zero site

    const int lds0  = 92160 + 2 * 128 * 256;   // 157696 (conv_dense<0>)
    const int ldsK1 = 2 * 23552 + 2 * 128 * 128; // 79872 -> 2 blocks/CU
    const int ldsK2 = 23552 + 2 * 32 * 128;      // 31744 -> 3-4 blocks/CU
    (void)hipFuncSetAttribute((const void*)conv_dense<0>,
                              hipFuncAttributeMaxDynamicSharedMemorySize, lds0);
    (void)hipFuncSetAttribute((const void*)conv_ks<1>,
                              hipFuncAttributeMaxDynamicSharedMemorySize, ldsK1);
    (void)hipFuncSetAttribute((const void*)conv_ks<2>,
                              hipFuncAttributeMaxDynamicSharedMemorySize, ldsK2);

    // stats (5376 B) + zrow (512 B) contiguous -> zero 1472 floats
    zerof<<<6, 256, 0, stream>>>(stats, 1472);

    long nx = (long)N0 * 256;
    cvt16<<<(int)((nx + 255) / 256), 256, 0, stream>>>(x, xh, nx);
    wtrans16<<<(27 * 256 * 128 + 255) / 256, 256, 0, stream>>>(w_s1, w1, 256, 128);
    wtrans16<<<(27 * 128 * 128 + 255) / 256, 256, 0, stream>>>(w11, wa1, 128, 128);
    wtrans16<<<(27 * 128 * 128 + 255) / 256, 256, 0, stream>>>(w12, wa2, 128, 128);
    wtrans16<<<(27 * 128 * 128 + 255) / 256, 256, 0, stream>>>(w21, wb1, 128, 128);
    wtrans16<<<(27 * 128 * 128 + 255) / 256, 256, 0, stream>>>(w22, wb2, 128, 128);
    wtrans16<<<(27 * 128 * 32 + 255) / 256, 256, 0, stream>>>(w_s2, w2, 128, 32);

    const float inv1 = 1.f / (float)M1, inv2 = 1.f / (float)M2;
    const int g1 = 3 * 72;              // 216 (conv_dense<0>)
    const int gk1 = 2 * 3 * 72;         // 432 (conv_ks<1>)
    const int gk2 = 2 * 5 * 72;         // 720 (conv_ks<2>)
    const long n4a = (long)M1 * 128 / 4;
    const long n4b = (long)M2 * 32 / 4;
    const int ga = (int)((n4a + 255) / 256);
    const int gb = (int)((n4b + 255) / 256);
    const int rp1 = M1 / 256;           // 108 rows per bnstats block
    const int rp2 = M2 / 256;           // 180

    // L1: spconv1 (256 -> 128), round-2 structure, stats fused
    conv_dense<0><<<g1, 512, lds0, stream>>>(xh, w1, zrow, cbuf, stats);
    bn_apply4<<<ga, 256, 0, stream>>>((float4*)cbuf, nullptr, stats, g_s1, b_s1,
                                      nullptr, fA, nullptr, n4a, 128, inv1);
    // Block 1 (K-split blocks, stats via bnstats)
    conv_ks<1><<<gk1, 512, ldsK1, stream>>>(fA, wa1, zrow, cbuf, cbuf2);
    bnstats<128><<<256, 512, 0, stream>>>(cbuf, cbuf2, stats + 256, rp1);
    bn_apply4<<<ga, 256, 0, stream>>>((float4*)cbuf, (float4*)cbuf2, stats + 256,
                                      g11, b11, nullptr, fB, nullptr, n4a, 128, inv1);
    conv_ks<1><<<gk1, 512, ldsK1, stream>>>(fB, wa2, zrow, cbuf, cbuf2);
    bnstats<128><<<256, 512, 0, stream>>>(cbuf, cbuf2, stats + 512, rp1);
    bn_apply4<<<ga, 256, 0, stream>>>((float4*)cbuf, (float4*)cbuf2, stats + 512,
                                      g12, b12, (const f16x4*)fA, fA, nullptr,
                                      n4a, 128, inv1);
    // Block 2
    conv_ks<1><<<gk1, 512, ldsK1, stream>>>(fA, wb1, zrow, cbuf, cbuf2);
    bnstats<128><<<256, 512, 0, stream>>>(cbuf, cbuf2, stats + 768, rp1);
    bn_apply4<<<ga, 256, 0, stream>>>((float4*)cbuf, (float4*)cbuf2, stats + 768,
                                      g21, b21, nullptr, fB, nullptr, n4a, 128, inv1);
    conv_ks<1><<<gk1, 512, ldsK1, stream>>>(fB, wb2, zrow, cbuf, cbuf2);
    bnstats<128><<<256, 512, 0, stream>>>(cbuf, cbuf2, stats + 1024, rp1);
    bn_apply4<<<ga, 256, 0, stream>>>((float4*)cbuf, (float4*)cbuf2, stats + 1024,
                                      g22, b22, (const f16x4*)fA, fA, nullptr,
                                      n4a, 128, inv1);
    // L6: spconv2 (128 -> 32), final fp32 output
    conv_ks<2><<<gk2, 512, ldsK2, stream>>>(fA, w2, zrow, cbuf, cbuf2);
    bnstats<32><<<256, 512, 0, stream>>>(cbuf, cbuf2, stats + 1280, rp2);
    bn_apply4<<<gb, 256, 0, stream>>>((float4*)cbuf, (float4*)cbuf2, stats + 1280,
                                      g_s2, b_s2, nullptr, nullptr, (float4*)d_out,
                                      n4b, 32, inv2);
}